// Round 6
// baseline (986.515 us; speedup 1.0000x reference)
//
#include <hip/hip_runtime.h>

typedef unsigned short u16;
typedef __bf16 bf16x8 __attribute__((ext_vector_type(8)));
typedef float f32x4 __attribute__((ext_vector_type(4)));
typedef u16 u16x8 __attribute__((ext_vector_type(8)));

union B8 { u16x8 u; bf16x8 b; };

__device__ __forceinline__ u16 f2b(float f){
  unsigned u = __float_as_uint(f);
  return (u16)((u + 0x7FFFu + ((u >> 16) & 1u)) >> 16);
}
__device__ __forceinline__ float b2f(u16 h){ return __uint_as_float(((unsigned)h) << 16); }

__device__ __forceinline__ void gload16(const u16* g, u16* l){
  __builtin_amdgcn_global_load_lds((const __attribute__((address_space(1))) void*)g,
                                   (__attribute__((address_space(3))) void*)l, 16, 0, 0);
}

// ---------------- prep kernel ----------------
// blocks: [0,4096) v->v_b single | [4096,4608) Wv->Wv_b single |
//         [4608,5120) transpose+dual-split Wq->WqT_pair, Wk->WkT_pair
__global__ __launch_bounds__(256) void prep_kernel(
    const float* __restrict__ v, const float* __restrict__ Wv,
    const float* __restrict__ Wq, const float* __restrict__ Wk,
    u16* __restrict__ v_b, u16* __restrict__ Wv_b,
    u16* __restrict__ WqT_pair, u16* __restrict__ WkT_pair)
{
  __shared__ float lds[64][65];
  const int blk = blockIdx.x, t = threadIdx.x;
  if (blk < 4608){
    const float* src; u16* dst; long base;
    if (blk < 4096){ src = v;  dst = v_b;  base = blk; }
    else           { src = Wv; dst = Wv_b; base = blk - 4096; }
    long i = base * 256 + t;
    float4 x0 = ((const float4*)src)[2 * i];
    float4 x1 = ((const float4*)src)[2 * i + 1];
    float xs[8] = {x0.x, x0.y, x0.z, x0.w, x1.x, x1.y, x1.z, x1.w};
    u16x8 h;
    #pragma unroll
    for (int j = 0; j < 8; j++) h[j] = f2b(xs[j]);
    ((u16x8*)dst)[i] = h;
  } else {
    int tt = blk - 4608;
    const float* W = (tt >> 8) ? Wk : Wq;
    u16* outp      = (tt >> 8) ? WkT_pair : WqT_pair;
    int t16 = tt & 255, g0 = (t16 >> 4) * 64, f0 = (t16 & 15) * 64;
    int c4 = (t & 15) * 4, r0 = t >> 4;
    #pragma unroll
    for (int it = 0; it < 4; it++){
      int r = r0 + it * 16;
      float4 x = *(const float4*)&W[(long)(g0 + r) * 1024 + f0 + c4];
      lds[r][c4] = x.x; lds[r][c4+1] = x.y; lds[r][c4+2] = x.z; lds[r][c4+3] = x.w;
    }
    __syncthreads();
    #pragma unroll
    for (int it = 0; it < 2; it++){
      int task = t + it * 256;           // 512 tasks = 64 f-rows x 8 g-groups
      int fl = task >> 3, gi = task & 7;
      u16x8 h, l;
      #pragma unroll
      for (int jj = 0; jj < 8; jj++){
        float xv = lds[gi * 8 + jj][fl];
        h[jj] = f2b(xv); l[jj] = f2b(xv - b2f(h[jj]));
      }
      u16* o = outp + (long)(f0 + fl) * 2048 + ((g0 >> 3) + gi) * 16;
      *(u16x8*)o = h;
      *(u16x8*)(o + 8) = l;
    }
  }
}

// ---------------- b[e] = sum_g Wk[g][e] * bq[g], from WkT_pair (hi+lo = fp32-ish) ----
__global__ __launch_bounds__(256) void bvec_kernel(
    const u16* __restrict__ WkT_pair, const float* __restrict__ bq, float* __restrict__ b)
{
  const int wave = threadIdx.x >> 6, lane = threadIdx.x & 63;
  const int e = blockIdx.x * 4 + wave;
  const u16* row = WkT_pair + (long)e * 2048;
  float acc = 0.f;
  #pragma unroll
  for (int ii = 0; ii < 2; ii++){
    int gi = lane * 2 + ii;            // 8-group index 0..127
    const u16* p = row + gi * 16;
    #pragma unroll
    for (int j = 0; j < 8; j++)
      acc += (b2f(p[j]) + b2f(p[j + 8])) * bq[gi * 8 + j];
  }
  #pragma unroll
  for (int off = 32; off > 0; off >>= 1) acc += __shfl_xor(acc, off, 64);
  if (lane == 0) b[e] = acc;
}

// ---------------- split q,k (dual paired) + kb[row] = k_row . b ----------------
__global__ __launch_bounds__(256) void split_qk_kernel(
    const float* __restrict__ q, const float* __restrict__ kk,
    const float* __restrict__ b,
    u16* __restrict__ q_pair, u16* __restrict__ k_pair, float* __restrict__ kb)
{
  const int blk = blockIdx.x, t = threadIdx.x;
  const bool isK = blk >= 4096;
  const float* src = isK ? kk : q;
  u16* dst = isK ? k_pair : q_pair;
  long base = isK ? blk - 4096 : blk;
  long i = base * 256 + t;
  float4 x0 = ((const float4*)src)[2 * i];
  float4 x1 = ((const float4*)src)[2 * i + 1];
  float xs[8] = {x0.x, x0.y, x0.z, x0.w, x1.x, x1.y, x1.z, x1.w};
  u16x8 h, l;
  #pragma unroll
  for (int j = 0; j < 8; j++){ h[j] = f2b(xs[j]); l[j] = f2b(xs[j] - b2f(h[j])); }
  ((u16x8*)dst)[2 * i]     = h;
  ((u16x8*)dst)[2 * i + 1] = l;
  if (isK){
    const int f = (t & 127) * 8;
    float d = 0.f;
    #pragma unroll
    for (int j = 0; j < 8; j++) d += xs[j] * b[f + j];
    #pragma unroll
    for (int off = 32; off > 0; off >>= 1) d += __shfl_xor(d, off, 64);
    __shared__ float red[4];
    if ((t & 63) == 0) red[t >> 6] = d;
    __syncthreads();
    if (t == 0)   kb[base * 2]     = red[0] + red[1];
    if (t == 128) kb[base * 2 + 1] = red[2] + red[3];
  }
}

// ---------------- reduce 4 fp32 partials -> dual pair ----------------
__global__ __launch_bounds__(256) void reduce_split_kernel(
    const float* __restrict__ part, u16* __restrict__ out_pair, long nper)
{
  long i = (long)blockIdx.x * 256 + threadIdx.x;   // 8-elem group index
  float s[8];
  #pragma unroll
  for (int j = 0; j < 8; j++) s[j] = 0.f;
  #pragma unroll
  for (int z = 0; z < 4; z++){
    float4 a0 = ((const float4*)(part + z * nper))[2 * i];
    float4 a1 = ((const float4*)(part + z * nper))[2 * i + 1];
    s[0]+=a0.x; s[1]+=a0.y; s[2]+=a0.z; s[3]+=a0.w;
    s[4]+=a1.x; s[5]+=a1.y; s[6]+=a1.z; s[7]+=a1.w;
  }
  u16x8 h, l;
  #pragma unroll
  for (int j = 0; j < 8; j++){ h[j] = f2b(s[j]); l[j] = f2b(s[j] - b2f(h[j])); }
  long e = (i * 8) >> 10;
  long g = i & 127;
  u16* o = out_pair + e * 2048 + g * 16;
  *(u16x8*)o = h;
  *(u16x8*)(o + 8) = l;
}

// ---------------- XCD-aware block remap (verified R3: FETCH 368->71 MB) ----------------
__device__ __forceinline__ void xcd_remap(int& tx, int& ty, int& tz){
  const int GX = gridDim.x, GY = gridDim.y;
  int b  = blockIdx.x + GX * (blockIdx.y + GY * blockIdx.z);
  int NB = GX * GY * gridDim.z;
  int rank = (b & 7) * (NB >> 3) + (b >> 3);
  int pz = GX * GY;
  tz = rank / pz;
  int r = rank - tz * pz;
  ty = r / GX;
  tx = r - ty * GX;
}

// ---------------- NT GEMM: C[m][n] = sum_k A[m][k] * B[n][k] ----------------
// EPI: 0 = +bias[n] (nullable), write paired hi|lo (batched by sOb)
//      2 = (+ per-(z,n) col bias if non-null) write fp32 C (batched by sOb)
//      3 = + residual, write fp32 C (batched)
//      4 = +bias[m], write bf16 batch-transposed: out[(n/seq)][m][n%seq] (coalesced in n)
constexpr int BM = 128, BN = 128, BK = 32;

__device__ __forceinline__ int lds1_idx(int row, int g){ return row * 32 + g * 8; }
__device__ __forceinline__ int lds2_idx(int row, int g){
  return row * 64 + (((g ^ (row & 7)) & 7) << 3);
}

template<bool DUAL, int EPI>
__global__ __launch_bounds__(256, DUAL ? 4 : 8)   // LDS: dual 32KB x4, single 16KB x8
void gemm_nt(const u16* __restrict__ A, const u16* __restrict__ Bm,
             const float* __restrict__ bias, const float* __restrict__ residual,
             void* __restrict__ out0,
             int M, int N, int K, int Krow,
             long sAb, long sBb, long sOb, long sRb, int seq)
{
  constexpr int RW = DUAL ? 64 : 32;
  __shared__ u16 lds[2][BM * RW];

  int tx, ty, tz; xcd_remap(tx, ty, tz);
  const int t = threadIdx.x;
  const int tileM = ty * BM;
  const int tileN = tx * BN;
  const long rs = DUAL ? 2L * Krow : (long)Krow;

  const u16* gA = A  + tz * sAb + (long)tileM * rs;
  const u16* gB = Bm + tz * sBb + (long)tileN * rs;

  const int wave = t >> 6, lane = t & 63;
  const int wm = (wave >> 1) * 64, wn = (wave & 1) * 64;
  const int lr = lane & 15;
  const int lg = lane >> 4;

  const u16 *pa, *pb;
  long jstride;
  int  ldsbase, ldsstep, nissue, kadv;
  if (DUAL){
    const int lr8 = lane >> 3, sl = lane & 7;
    const int g = sl ^ lr8;
    pa = gA + (long)(wave * 32 + lr8) * rs + g * 8;
    pb = gB + (long)(wave * 32 + lr8) * rs + g * 8;
    jstride = 8 * rs;
    ldsbase = (wave * 32) * 64; ldsstep = 8 * 64;
    nissue = 4; kadv = 64;
  } else {
    pa = gA + (long)(wave * 32 + (lane >> 2)) * rs + (lane & 3) * 8;
    pb = gB + (long)(wave * 32 + (lane >> 2)) * rs + (lane & 3) * 8;
    jstride = 16 * rs;
    ldsbase = (wave * 32) * 32; ldsstep = 16 * 32;
    nissue = 2; kadv = 32;
  }

  f32x4 acc[4][4] = {};

  for (int k0 = 0; k0 < K; k0 += BK){
    __syncthreads();
    #pragma unroll 4
    for (int j = 0; j < nissue; j++){
      gload16(pa + j * jstride, &lds[0][ldsbase + j * ldsstep]);
      gload16(pb + j * jstride, &lds[1][ldsbase + j * ldsstep]);
    }
    pa += kadv; pb += kadv;
    __syncthreads();

    if (DUAL){
      B8 ah[4], al[4], bh[4], bl[4];
      #pragma unroll
      for (int mt = 0; mt < 4; mt++){
        int row = wm + mt * 16 + lr;
        ah[mt].u = *(const u16x8*)&lds[0][lds2_idx(row, lg * 2)];
        al[mt].u = *(const u16x8*)&lds[0][lds2_idx(row, lg * 2 + 1)];
      }
      #pragma unroll
      for (int nt = 0; nt < 4; nt++){
        int row = wn + nt * 16 + lr;
        bh[nt].u = *(const u16x8*)&lds[1][lds2_idx(row, lg * 2)];
        bl[nt].u = *(const u16x8*)&lds[1][lds2_idx(row, lg * 2 + 1)];
      }
      #pragma unroll
      for (int mt = 0; mt < 4; mt++){
        #pragma unroll
        for (int nt = 0; nt < 4; nt++){
          acc[mt][nt] = __builtin_amdgcn_mfma_f32_16x16x32_bf16(ah[mt].b, bh[nt].b, acc[mt][nt], 0, 0, 0);
          acc[mt][nt] = __builtin_amdgcn_mfma_f32_16x16x32_bf16(ah[mt].b, bl[nt].b, acc[mt][nt], 0, 0, 0);
          acc[mt][nt] = __builtin_amdgcn_mfma_f32_16x16x32_bf16(al[mt].b, bh[nt].b, acc[mt][nt], 0, 0, 0);
        }
      }
    } else {
      B8 af[4], bf[4];
      #pragma unroll
      for (int mt = 0; mt < 4; mt++)
        af[mt].u = *(const u16x8*)&lds[0][lds1_idx(wm + mt * 16 + lr, lg)];
      #pragma unroll
      for (int nt = 0; nt < 4; nt++)
        bf[nt].u = *(const u16x8*)&lds[1][lds1_idx(wn + nt * 16 + lr, lg)];
      #pragma unroll
      for (int mt = 0; mt < 4; mt++)
        #pragma unroll
        for (int nt = 0; nt < 4; nt++)
          acc[mt][nt] = __builtin_amdgcn_mfma_f32_16x16x32_bf16(af[mt].b, bf[nt].b, acc[mt][nt], 0, 0, 0);
    }
  }

  // epilogue: C/D layout col=lane&15, row=(lane>>4)*4+reg  [m89-verified]
  const int rq = lg * 4;
  #pragma unroll
  for (int nt = 0; nt < 4; nt++){
    const int n = tileN + wn + nt * 16 + lr;
    float bv = 0.f;
    if (EPI == 0 && bias) bv = bias[n];
    if (EPI == 2 && bias) bv = bias[(long)tz * N + n];
    #pragma unroll
    for (int mt = 0; mt < 4; mt++){
      #pragma unroll
      for (int r = 0; r < 4; r++){
        const int m = tileM + wm + mt * 16 + rq + r;
        float val = acc[mt][nt][r] + bv;
        if (EPI == 0){
          u16 h = f2b(val);
          u16* o = (u16*)out0 + (long)tz * sOb + (long)m * 2 * N + ((n >> 3) << 4) + (n & 7);
          o[0] = h;
          o[8] = f2b(val - b2f(h));
        } else if (EPI == 2){
          ((float*)out0)[(long)tz * sOb + (long)m * N + n] = val;
        } else if (EPI == 3){
          float res = residual[(long)tz * sRb + (long)m * N + n];
          ((float*)out0)[(long)tz * sOb + (long)m * N + n] = val + res;
        } else {  // EPI == 4: transposed-coalesced bf16, bias by m
          if (bias) val += bias[m];
          long idx = (long)(n / seq) * ((long)M * seq) + (long)m * seq + (n % seq);
          ((u16*)out0)[idx] = f2b(val);
        }
      }
    }
  }
}

// ---------------- row softmax: fp32 scores -> bf16 probs (n == 2048) ----------------
__global__ __launch_bounds__(256)
void softmax_kernel(const float* __restrict__ S, u16* __restrict__ P, int n){
  const long row = blockIdx.x;
  const float* r = S + row * (long)n;
  const int t = threadIdx.x;
  float v[8];
  float mx = -3.0e38f;
  #pragma unroll
  for (int i = 0; i < 8; i++){ v[i] = r[t + (i << 8)]; mx = fmaxf(mx, v[i]); }
  #pragma unroll
  for (int off = 32; off > 0; off >>= 1) mx = fmaxf(mx, __shfl_xor(mx, off, 64));
  __shared__ float red[8];
  const int wave = t >> 6;
  if ((t & 63) == 0) red[wave] = mx;
  __syncthreads();
  mx = fmaxf(fmaxf(red[0], red[1]), fmaxf(red[2], red[3]));
  float s = 0.f;
  #pragma unroll
  for (int i = 0; i < 8; i++){ v[i] = __expf(v[i] - mx); s += v[i]; }
  #pragma unroll
  for (int off = 32; off > 0; off >>= 1) s += __shfl_xor(s, off, 64);
  if ((t & 63) == 0) red[4 + wave] = s;
  __syncthreads();
  s = red[4] + red[5] + red[6] + red[7];
  const float inv = 1.f / s;
  u16* pr = P + row * (long)n;
  #pragma unroll
  for (int i = 0; i < 8; i++) pr[t + (i << 8)] = f2b(v[i] * inv);
}

extern "C" void kernel_launch(void* const* d_in, const int* in_sizes, int n_in,
                              void* d_out, int out_size, void* d_ws, size_t ws_size,
                              hipStream_t stream){
  (void)in_sizes; (void)n_in; (void)out_size; (void)ws_size;
  const float* q  = (const float*)d_in[0];
  const float* k  = (const float*)d_in[1];
  const float* v  = (const float*)d_in[2];
  const float* Wq = (const float*)d_in[3];
  const float* bq = (const float*)d_in[4];
  const float* Wk = (const float*)d_in[5];
  // bk enters only a row-constant term: softmax-invariant, dropped
  const float* Wv = (const float*)d_in[7];
  const float* bv = (const float*)d_in[8];
  float* out = (float*)d_out;

  const int B = 4, S = 2048, F = 1024;
  const long NSF = (long)B * S * F;   // 8 Mi
  const long NFF = (long)F * F;       // 1 Mi
  const long NSS = (long)B * S * S;   // 16 Mi

  char* w = (char*)d_ws;
  auto alloc = [&](long bytes) -> char* {
    char* p = w; w += (bytes + 255) & ~(long)255; return p;
  };
  // persistent
  u16*   tmp_pair = (u16*)alloc(2 * NSF * 2);   // (q M^T) dual pair, 33.5 MB
  u16*   k_pair   = (u16*)alloc(2 * NSF * 2);   // raw k dual pair,   33.5 MB
  u16*   vpT      = (u16*)alloc(NSF * 2);       // 16.8 MB
  float* kb       = (float*)alloc((long)B * S * 4);
  // zone2 (100.7 MB): scores+attn alias the phase-1 temporaries
  char* zone2 = alloc(NSS * 2 + NSS * 4);
  u16*   attn   = (u16*)zone2;
  float* scores = (float*)(zone2 + NSS * 2);
  // phase-1 occupants (dead before their aliasing writer runs):
  u16*   q_pair   = (u16*)zone2;                        // == attn region
  char*  z3       = zone2 + NSS * 2;                    // == scores region
  u16*   v_b      = (u16*)z3;                           // 16.8 MB
  u16*   Wv_b     = (u16*)(z3 + NSF * 2);               // 2.1 MB
  u16*   WqT_pair = (u16*)(z3 + NSF * 2 + NFF * 2);     // 4.2 MB
  u16*   WkT_pair = WqT_pair + 2 * NFF;                 // 4.2 MB
  float* b_vec    = (float*)(WkT_pair + 2 * NFF);       // 4 KB
  float* Mt_part  = (float*)((char*)b_vec + 4096);      // 4 x 4.2 MB
  u16*   Mt_pair  = (u16*)((char*)Mt_part + 4 * NFF * 4);

  dim3 blk(256);

  // 1) prep: v/Wv split, Wq/Wk transpose+dual-split
  prep_kernel<<<dim3(5120), blk, 0, stream>>>(
      v, Wv, Wq, Wk, v_b, Wv_b, WqT_pair, WkT_pair);

  // 2) b = Wk^T bq (parallel, from WkT_pair hi+lo)
  bvec_kernel<<<dim3(256), blk, 0, stream>>>(WkT_pair, bq, b_vec);

  // 3) vpT[b][g][s] = (Wv v^T + bv)  — A=Wv, B=v, transposed-coalesced epilogue
  gemm_nt<false, 4><<<dim3((B * S) / BN, F / BM, 1), blk, 0, stream>>>(
      Wv_b, v_b, bv, nullptr, vpT,
      F, B * S, F, F, 0, 0, 0, 0, S);

  // 4) split q,k (dual) + kb[row] = k_row . b
  split_qk_kernel<<<dim3(8192), blk, 0, stream>>>(q, k, b_vec, q_pair, k_pair, kb);

  // 5) Mt partials: Mt[e,f] = sum_g Wk[g,e]Wq[g,f], K split 4x256
  gemm_nt<true, 2><<<dim3(F / BN, F / BM, 4), blk, 0, stream>>>(
      WkT_pair, WqT_pair, nullptr, nullptr, Mt_part,
      F, F, 256, F, 512, 512, NFF, 0, S);

  // 6) Mt_pair = dual-split(sum of partials)
  reduce_split_kernel<<<dim3(512), blk, 0, stream>>>(Mt_part, Mt_pair, NFF);

  // 7) tmp = q @ Mt^T (dual, no bias), paired out
  gemm_nt<true, 0><<<dim3(F / BN, (B * S) / BM, 1), blk, 0, stream>>>(
      q_pair, Mt_pair, nullptr, nullptr, tmp_pair,
      B * S, F, F, F, 0, 0, 0, 0, S);

  // 8) scores[z] = tmp[z] @ k[z]^T + kb[z][:]  (fp32)
  gemm_nt<true, 2><<<dim3(S / BN, S / BM, B), blk, 0, stream>>>(
      tmp_pair, k_pair, kb, nullptr, scores,
      S, S, F, F, (long)S * 2 * F, (long)S * 2 * F, (long)S * S, 0, S);

  // 9) attn = softmax(scores) (bf16)
  softmax_kernel<<<dim3(B * S), blk, 0, stream>>>(scores, attn, S);

  // 10) out[z] = attn[z] @ vp[z] + q[z]
  gemm_nt<false, 3><<<dim3(F / BN, S / BM, B), blk, 0, stream>>>(
      attn, vpT, nullptr, q, out,
      S, F, S, S, (long)S * S, (long)F * S, (long)S * F, (long)S * F, S);
}

// Round 7
// 445.668 us; speedup vs baseline: 2.2136x; 2.2136x over previous
//
#include <hip/hip_runtime.h>

typedef unsigned short u16;
typedef __bf16 bf16x8 __attribute__((ext_vector_type(8)));
typedef float f32x4 __attribute__((ext_vector_type(4)));
typedef u16 u16x8 __attribute__((ext_vector_type(8)));

union B8 { u16x8 u; bf16x8 b; };

__device__ __forceinline__ u16 f2b(float f){
  unsigned u = __float_as_uint(f);
  return (u16)((u + 0x7FFFu + ((u >> 16) & 1u)) >> 16);
}
__device__ __forceinline__ float b2f(u16 h){ return __uint_as_float(((unsigned)h) << 16); }

__device__ __forceinline__ void gload16(const u16* g, u16* l){
  __builtin_amdgcn_global_load_lds((const __attribute__((address_space(1))) void*)g,
                                   (__attribute__((address_space(3))) void*)l, 16, 0, 0);
}

// ---------------- prep kernel ----------------
// blocks: [0,4096) v->v_b single | [4096,4608) Wv->Wv_b single |
//         [4608,5120) transpose+dual-split Wq->WqT_pair, Wk->WkT_pair
__global__ __launch_bounds__(256) void prep_kernel(
    const float* __restrict__ v, const float* __restrict__ Wv,
    const float* __restrict__ Wq, const float* __restrict__ Wk,
    u16* __restrict__ v_b, u16* __restrict__ Wv_b,
    u16* __restrict__ WqT_pair, u16* __restrict__ WkT_pair)
{
  __shared__ float lds[64][65];
  const int blk = blockIdx.x, t = threadIdx.x;
  if (blk < 4608){
    const float* src; u16* dst; long base;
    if (blk < 4096){ src = v;  dst = v_b;  base = blk; }
    else           { src = Wv; dst = Wv_b; base = blk - 4096; }
    long i = base * 256 + t;
    float4 x0 = ((const float4*)src)[2 * i];
    float4 x1 = ((const float4*)src)[2 * i + 1];
    float xs[8] = {x0.x, x0.y, x0.z, x0.w, x1.x, x1.y, x1.z, x1.w};
    u16x8 h;
    #pragma unroll
    for (int j = 0; j < 8; j++) h[j] = f2b(xs[j]);
    ((u16x8*)dst)[i] = h;
  } else {
    int tt = blk - 4608;
    const float* W = (tt >> 8) ? Wk : Wq;
    u16* outp      = (tt >> 8) ? WkT_pair : WqT_pair;
    int t16 = tt & 255, g0 = (t16 >> 4) * 64, f0 = (t16 & 15) * 64;
    int c4 = (t & 15) * 4, r0 = t >> 4;
    #pragma unroll
    for (int it = 0; it < 4; it++){
      int r = r0 + it * 16;
      float4 x = *(const float4*)&W[(long)(g0 + r) * 1024 + f0 + c4];
      lds[r][c4] = x.x; lds[r][c4+1] = x.y; lds[r][c4+2] = x.z; lds[r][c4+3] = x.w;
    }
    __syncthreads();
    #pragma unroll
    for (int it = 0; it < 2; it++){
      int task = t + it * 256;           // 512 tasks = 64 f-rows x 8 g-groups
      int fl = task >> 3, gi = task & 7;
      u16x8 h, l;
      #pragma unroll
      for (int jj = 0; jj < 8; jj++){
        float xv = lds[gi * 8 + jj][fl];
        h[jj] = f2b(xv); l[jj] = f2b(xv - b2f(h[jj]));
      }
      u16* o = outp + (long)(f0 + fl) * 2048 + ((g0 >> 3) + gi) * 16;
      *(u16x8*)o = h;
      *(u16x8*)(o + 8) = l;
    }
  }
}

// ---------------- b[e] = sum_g Wk[g][e] * bq[g], from WkT_pair (hi+lo = fp32-ish) ----
__global__ __launch_bounds__(256) void bvec_kernel(
    const u16* __restrict__ WkT_pair, const float* __restrict__ bq, float* __restrict__ b)
{
  const int wave = threadIdx.x >> 6, lane = threadIdx.x & 63;
  const int e = blockIdx.x * 4 + wave;
  const u16* row = WkT_pair + (long)e * 2048;
  float acc = 0.f;
  #pragma unroll
  for (int ii = 0; ii < 2; ii++){
    int gi = lane * 2 + ii;            // 8-group index 0..127
    const u16* p = row + gi * 16;
    #pragma unroll
    for (int j = 0; j < 8; j++)
      acc += (b2f(p[j]) + b2f(p[j + 8])) * bq[gi * 8 + j];
  }
  #pragma unroll
  for (int off = 32; off > 0; off >>= 1) acc += __shfl_xor(acc, off, 64);
  if (lane == 0) b[e] = acc;
}

// ---------------- split q,k (dual paired) + kb[row] = k_row . b ----------------
__global__ __launch_bounds__(256) void split_qk_kernel(
    const float* __restrict__ q, const float* __restrict__ kk,
    const float* __restrict__ b,
    u16* __restrict__ q_pair, u16* __restrict__ k_pair, float* __restrict__ kb)
{
  const int blk = blockIdx.x, t = threadIdx.x;
  const bool isK = blk >= 4096;
  const float* src = isK ? kk : q;
  u16* dst = isK ? k_pair : q_pair;
  long base = isK ? blk - 4096 : blk;
  long i = base * 256 + t;
  float4 x0 = ((const float4*)src)[2 * i];
  float4 x1 = ((const float4*)src)[2 * i + 1];
  float xs[8] = {x0.x, x0.y, x0.z, x0.w, x1.x, x1.y, x1.z, x1.w};
  u16x8 h, l;
  #pragma unroll
  for (int j = 0; j < 8; j++){ h[j] = f2b(xs[j]); l[j] = f2b(xs[j] - b2f(h[j])); }
  ((u16x8*)dst)[2 * i]     = h;
  ((u16x8*)dst)[2 * i + 1] = l;
  if (isK){
    const int f = (t & 127) * 8;
    float d = 0.f;
    #pragma unroll
    for (int j = 0; j < 8; j++) d += xs[j] * b[f + j];
    #pragma unroll
    for (int off = 32; off > 0; off >>= 1) d += __shfl_xor(d, off, 64);
    __shared__ float red[4];
    if ((t & 63) == 0) red[t >> 6] = d;
    __syncthreads();
    if (t == 0)   kb[base * 2]     = red[0] + red[1];
    if (t == 128) kb[base * 2 + 1] = red[2] + red[3];
  }
}

// ---------------- reduce 4 fp32 partials -> dual pair ----------------
__global__ __launch_bounds__(256) void reduce_split_kernel(
    const float* __restrict__ part, u16* __restrict__ out_pair, long nper)
{
  long i = (long)blockIdx.x * 256 + threadIdx.x;   // 8-elem group index
  float s[8];
  #pragma unroll
  for (int j = 0; j < 8; j++) s[j] = 0.f;
  #pragma unroll
  for (int z = 0; z < 4; z++){
    float4 a0 = ((const float4*)(part + z * nper))[2 * i];
    float4 a1 = ((const float4*)(part + z * nper))[2 * i + 1];
    s[0]+=a0.x; s[1]+=a0.y; s[2]+=a0.z; s[3]+=a0.w;
    s[4]+=a1.x; s[5]+=a1.y; s[6]+=a1.z; s[7]+=a1.w;
  }
  u16x8 h, l;
  #pragma unroll
  for (int j = 0; j < 8; j++){ h[j] = f2b(s[j]); l[j] = f2b(s[j] - b2f(h[j])); }
  long e = (i * 8) >> 10;
  long g = i & 127;
  u16* o = out_pair + e * 2048 + g * 16;
  *(u16x8*)o = h;
  *(u16x8*)(o + 8) = l;
}

// ---------------- XCD-aware block remap (verified R3: FETCH 368->71 MB) ----------------
__device__ __forceinline__ void xcd_remap(int& tx, int& ty, int& tz){
  const int GX = gridDim.x, GY = gridDim.y;
  int b  = blockIdx.x + GX * (blockIdx.y + GY * blockIdx.z);
  int NB = GX * GY * gridDim.z;
  int rank = (b & 7) * (NB >> 3) + (b >> 3);
  int pz = GX * GY;
  tz = rank / pz;
  int r = rank - tz * pz;
  ty = r / GX;
  tx = r - ty * GX;
}

// ---------------- NT GEMM: C[m][n] = sum_k A[m][k] * B[n][k] ----------------
// EPI: 0 = +bias[n] (nullable), write paired hi|lo (batched by sOb)
//      2 = (+ per-(z,n) col bias if non-null) write fp32 C (batched by sOb)
//      3 = + residual, write fp32 C (batched)
//      4 = +bias[m], write bf16 batch-transposed: out[(n/seq)][m][n%seq] (coalesced in n)
constexpr int BM = 128, BN = 128, BK = 32;

__device__ __forceinline__ int lds1_idx(int row, int g){ return row * 32 + g * 8; }
__device__ __forceinline__ int lds2_idx(int row, int g){
  return row * 64 + (((g ^ (row & 7)) & 7) << 3);
}

// NOTE: 4 blocks/CU for BOTH paths. R6's (256,8) on single path capped the
// unified VGPR+AGPR budget at 64/wave -> acc[4][4] spilled to scratch
// (VGPR_Count 32, WRITE_SIZE 1.34 GB, MfmaUtil 3%, 455 us). Do not raise.
template<bool DUAL, int EPI>
__global__ __launch_bounds__(256, 4)
void gemm_nt(const u16* __restrict__ A, const u16* __restrict__ Bm,
             const float* __restrict__ bias, const float* __restrict__ residual,
             void* __restrict__ out0,
             int M, int N, int K, int Krow,
             long sAb, long sBb, long sOb, long sRb, int seq)
{
  constexpr int RW = DUAL ? 64 : 32;
  __shared__ u16 lds[2][BM * RW];

  int tx, ty, tz; xcd_remap(tx, ty, tz);
  const int t = threadIdx.x;
  const int tileM = ty * BM;
  const int tileN = tx * BN;
  const long rs = DUAL ? 2L * Krow : (long)Krow;

  const u16* gA = A  + tz * sAb + (long)tileM * rs;
  const u16* gB = Bm + tz * sBb + (long)tileN * rs;

  const int wave = t >> 6, lane = t & 63;
  const int wm = (wave >> 1) * 64, wn = (wave & 1) * 64;
  const int lr = lane & 15;
  const int lg = lane >> 4;

  const u16 *pa, *pb;
  long jstride;
  int  ldsbase, ldsstep, nissue, kadv;
  if (DUAL){
    const int lr8 = lane >> 3, sl = lane & 7;
    const int g = sl ^ lr8;
    pa = gA + (long)(wave * 32 + lr8) * rs + g * 8;
    pb = gB + (long)(wave * 32 + lr8) * rs + g * 8;
    jstride = 8 * rs;
    ldsbase = (wave * 32) * 64; ldsstep = 8 * 64;
    nissue = 4; kadv = 64;
  } else {
    pa = gA + (long)(wave * 32 + (lane >> 2)) * rs + (lane & 3) * 8;
    pb = gB + (long)(wave * 32 + (lane >> 2)) * rs + (lane & 3) * 8;
    jstride = 16 * rs;
    ldsbase = (wave * 32) * 32; ldsstep = 16 * 32;
    nissue = 2; kadv = 32;
  }

  f32x4 acc[4][4] = {};

  for (int k0 = 0; k0 < K; k0 += BK){
    __syncthreads();
    #pragma unroll 4
    for (int j = 0; j < nissue; j++){
      gload16(pa + j * jstride, &lds[0][ldsbase + j * ldsstep]);
      gload16(pb + j * jstride, &lds[1][ldsbase + j * ldsstep]);
    }
    pa += kadv; pb += kadv;
    __syncthreads();

    if (DUAL){
      B8 ah[4], al[4], bh[4], bl[4];
      #pragma unroll
      for (int mt = 0; mt < 4; mt++){
        int row = wm + mt * 16 + lr;
        ah[mt].u = *(const u16x8*)&lds[0][lds2_idx(row, lg * 2)];
        al[mt].u = *(const u16x8*)&lds[0][lds2_idx(row, lg * 2 + 1)];
      }
      #pragma unroll
      for (int nt = 0; nt < 4; nt++){
        int row = wn + nt * 16 + lr;
        bh[nt].u = *(const u16x8*)&lds[1][lds2_idx(row, lg * 2)];
        bl[nt].u = *(const u16x8*)&lds[1][lds2_idx(row, lg * 2 + 1)];
      }
      #pragma unroll
      for (int mt = 0; mt < 4; mt++){
        #pragma unroll
        for (int nt = 0; nt < 4; nt++){
          acc[mt][nt] = __builtin_amdgcn_mfma_f32_16x16x32_bf16(ah[mt].b, bh[nt].b, acc[mt][nt], 0, 0, 0);
          acc[mt][nt] = __builtin_amdgcn_mfma_f32_16x16x32_bf16(ah[mt].b, bl[nt].b, acc[mt][nt], 0, 0, 0);
          acc[mt][nt] = __builtin_amdgcn_mfma_f32_16x16x32_bf16(al[mt].b, bh[nt].b, acc[mt][nt], 0, 0, 0);
        }
      }
    } else {
      B8 af[4], bf[4];
      #pragma unroll
      for (int mt = 0; mt < 4; mt++)
        af[mt].u = *(const u16x8*)&lds[0][lds1_idx(wm + mt * 16 + lr, lg)];
      #pragma unroll
      for (int nt = 0; nt < 4; nt++)
        bf[nt].u = *(const u16x8*)&lds[1][lds1_idx(wn + nt * 16 + lr, lg)];
      #pragma unroll
      for (int mt = 0; mt < 4; mt++)
        #pragma unroll
        for (int nt = 0; nt < 4; nt++)
          acc[mt][nt] = __builtin_amdgcn_mfma_f32_16x16x32_bf16(af[mt].b, bf[nt].b, acc[mt][nt], 0, 0, 0);
    }
  }

  // epilogue: C/D layout col=lane&15, row=(lane>>4)*4+reg  [m89-verified]
  const int rq = lg * 4;
  #pragma unroll
  for (int nt = 0; nt < 4; nt++){
    const int n = tileN + wn + nt * 16 + lr;
    float bv = 0.f;
    if (EPI == 0 && bias) bv = bias[n];
    if (EPI == 2 && bias) bv = bias[(long)tz * N + n];
    #pragma unroll
    for (int mt = 0; mt < 4; mt++){
      #pragma unroll
      for (int r = 0; r < 4; r++){
        const int m = tileM + wm + mt * 16 + rq + r;
        float val = acc[mt][nt][r] + bv;
        if (EPI == 0){
          u16 h = f2b(val);
          u16* o = (u16*)out0 + (long)tz * sOb + (long)m * 2 * N + ((n >> 3) << 4) + (n & 7);
          o[0] = h;
          o[8] = f2b(val - b2f(h));
        } else if (EPI == 2){
          ((float*)out0)[(long)tz * sOb + (long)m * N + n] = val;
        } else if (EPI == 3){
          float res = residual[(long)tz * sRb + (long)m * N + n];
          ((float*)out0)[(long)tz * sOb + (long)m * N + n] = val + res;
        } else {  // EPI == 4: transposed-coalesced bf16, bias by m
          if (bias) val += bias[m];
          long idx = (long)(n / seq) * ((long)M * seq) + (long)m * seq + (n % seq);
          ((u16*)out0)[idx] = f2b(val);
        }
      }
    }
  }
}

// ---------------- row softmax: fp32 scores -> bf16 probs (n == 2048) ----------------
__global__ __launch_bounds__(256)
void softmax_kernel(const float* __restrict__ S, u16* __restrict__ P, int n){
  const long row = blockIdx.x;
  const float* r = S + row * (long)n;
  const int t = threadIdx.x;
  float v[8];
  float mx = -3.0e38f;
  #pragma unroll
  for (int i = 0; i < 8; i++){ v[i] = r[t + (i << 8)]; mx = fmaxf(mx, v[i]); }
  #pragma unroll
  for (int off = 32; off > 0; off >>= 1) mx = fmaxf(mx, __shfl_xor(mx, off, 64));
  __shared__ float red[8];
  const int wave = t >> 6;
  if ((t & 63) == 0) red[wave] = mx;
  __syncthreads();
  mx = fmaxf(fmaxf(red[0], red[1]), fmaxf(red[2], red[3]));
  float s = 0.f;
  #pragma unroll
  for (int i = 0; i < 8; i++){ v[i] = __expf(v[i] - mx); s += v[i]; }
  #pragma unroll
  for (int off = 32; off > 0; off >>= 1) s += __shfl_xor(s, off, 64);
  if ((t & 63) == 0) red[4 + wave] = s;
  __syncthreads();
  s = red[4] + red[5] + red[6] + red[7];
  const float inv = 1.f / s;
  u16* pr = P + row * (long)n;
  #pragma unroll
  for (int i = 0; i < 8; i++) pr[t + (i << 8)] = f2b(v[i] * inv);
}

extern "C" void kernel_launch(void* const* d_in, const int* in_sizes, int n_in,
                              void* d_out, int out_size, void* d_ws, size_t ws_size,
                              hipStream_t stream){
  (void)in_sizes; (void)n_in; (void)out_size; (void)ws_size;
  const float* q  = (const float*)d_in[0];
  const float* k  = (const float*)d_in[1];
  const float* v  = (const float*)d_in[2];
  const float* Wq = (const float*)d_in[3];
  const float* bq = (const float*)d_in[4];
  const float* Wk = (const float*)d_in[5];
  // bk enters only a row-constant term: softmax-invariant, dropped
  const float* Wv = (const float*)d_in[7];
  const float* bv = (const float*)d_in[8];
  float* out = (float*)d_out;

  const int B = 4, S = 2048, F = 1024;
  const long NSF = (long)B * S * F;   // 8 Mi
  const long NFF = (long)F * F;       // 1 Mi
  const long NSS = (long)B * S * S;   // 16 Mi

  char* w = (char*)d_ws;
  auto alloc = [&](long bytes) -> char* {
    char* p = w; w += (bytes + 255) & ~(long)255; return p;
  };
  // persistent
  u16*   tmp_pair = (u16*)alloc(2 * NSF * 2);   // (q M^T) dual pair, 33.5 MB
  u16*   k_pair   = (u16*)alloc(2 * NSF * 2);   // raw k dual pair,   33.5 MB
  u16*   vpT      = (u16*)alloc(NSF * 2);       // 16.8 MB
  float* kb       = (float*)alloc((long)B * S * 4);
  // zone2 (100.7 MB): scores+attn alias the phase-1 temporaries
  char* zone2 = alloc(NSS * 2 + NSS * 4);
  u16*   attn   = (u16*)zone2;
  float* scores = (float*)(zone2 + NSS * 2);
  // phase-1 occupants (dead before their aliasing writer runs):
  u16*   q_pair   = (u16*)zone2;                        // == attn region
  char*  z3       = zone2 + NSS * 2;                    // == scores region
  u16*   v_b      = (u16*)z3;                           // 16.8 MB
  u16*   Wv_b     = (u16*)(z3 + NSF * 2);               // 2.1 MB
  u16*   WqT_pair = (u16*)(z3 + NSF * 2 + NFF * 2);     // 4.2 MB
  u16*   WkT_pair = WqT_pair + 2 * NFF;                 // 4.2 MB
  float* b_vec    = (float*)(WkT_pair + 2 * NFF);       // 4 KB
  float* Mt_part  = (float*)((char*)b_vec + 4096);      // 4 x 4.2 MB
  u16*   Mt_pair  = (u16*)((char*)Mt_part + 4 * NFF * 4);

  dim3 blk(256);

  // 1) prep: v/Wv split, Wq/Wk transpose+dual-split
  prep_kernel<<<dim3(5120), blk, 0, stream>>>(
      v, Wv, Wq, Wk, v_b, Wv_b, WqT_pair, WkT_pair);

  // 2) b = Wk^T bq (parallel, from WkT_pair hi+lo)
  bvec_kernel<<<dim3(256), blk, 0, stream>>>(WkT_pair, bq, b_vec);

  // 3) vpT[b][g][s] = (Wv v^T + bv)  — A=Wv, B=v, transposed-coalesced epilogue
  gemm_nt<false, 4><<<dim3((B * S) / BN, F / BM, 1), blk, 0, stream>>>(
      Wv_b, v_b, bv, nullptr, vpT,
      F, B * S, F, F, 0, 0, 0, 0, S);

  // 4) split q,k (dual) + kb[row] = k_row . b
  split_qk_kernel<<<dim3(8192), blk, 0, stream>>>(q, k, b_vec, q_pair, k_pair, kb);

  // 5) Mt partials: Mt[e,f] = sum_g Wk[g,e]Wq[g,f], K split 4x256
  gemm_nt<true, 2><<<dim3(F / BN, F / BM, 4), blk, 0, stream>>>(
      WkT_pair, WqT_pair, nullptr, nullptr, Mt_part,
      F, F, 256, F, 512, 512, NFF, 0, S);

  // 6) Mt_pair = dual-split(sum of partials)
  reduce_split_kernel<<<dim3(512), blk, 0, stream>>>(Mt_part, Mt_pair, NFF);

  // 7) tmp = q @ Mt^T (dual, no bias), paired out
  gemm_nt<true, 0><<<dim3(F / BN, (B * S) / BM, 1), blk, 0, stream>>>(
      q_pair, Mt_pair, nullptr, nullptr, tmp_pair,
      B * S, F, F, F, 0, 0, 0, 0, S);

  // 8) scores[z] = tmp[z] @ k[z]^T + kb[z][:]  (fp32)
  gemm_nt<true, 2><<<dim3(S / BN, S / BM, B), blk, 0, stream>>>(
      tmp_pair, k_pair, kb, nullptr, scores,
      S, S, F, F, (long)S * 2 * F, (long)S * 2 * F, (long)S * S, 0, S);

  // 9) attn = softmax(scores) (bf16)
  softmax_kernel<<<dim3(B * S), blk, 0, stream>>>(scores, attn, S);

  // 10) out[z] = attn[z] @ vp[z] + q[z]
  gemm_nt<false, 3><<<dim3(F / BN, S / BM, B), blk, 0, stream>>>(
      attn, vpT, nullptr, q, out,
      S, F, S, S, (long)S * S, (long)F * S, (long)S * F, (long)S * F, S);
}